// Round 2
// baseline (1319.979 us; speedup 1.0000x reference)
//
#include <hip/hip_runtime.h>
#include <math.h>

#define B_N 256
#define T_N 1024
#define D_N 128
#define H_N 256

__device__ __forceinline__ float sigmoid_f(float z) {
    return 1.0f / (1.0f + __expf(-z));
}

// Generic small dense layer with relu: out = relu(in @ W + bias)
// 4 rows per thread (r0..r0+3), NCPT cols per thread (tc*NCPT..).
// in/out are LDS row-major with strides INS/OUTS. W read from global (cached).
template<int K, int N, int NCPT, int INS, int OUTS>
__device__ __forceinline__ void dense_relu(const float* __restrict__ W,
                                           const float* __restrict__ bias,
                                           const float* __restrict__ in,
                                           float* __restrict__ outb,
                                           int r0, int tc)
{
    const int j0 = tc * NCPT;
    if (j0 >= N) return;
    float acc[4][NCPT];
    #pragma unroll
    for (int i = 0; i < 4; ++i)
        #pragma unroll
        for (int c = 0; c < NCPT; ++c) acc[i][c] = 0.0f;

    #pragma unroll 4
    for (int k = 0; k < K; ++k) {
        float a[4];
        #pragma unroll
        for (int i = 0; i < 4; ++i) a[i] = in[(r0 + i) * INS + k];
        float w[NCPT];
        if constexpr (NCPT == 4) {
            const float4 wv = *reinterpret_cast<const float4*>(W + (size_t)k * N + j0);
            w[0] = wv.x; w[1] = wv.y; w[2] = wv.z; w[3] = wv.w;
        } else {
            const float2 wv = *reinterpret_cast<const float2*>(W + (size_t)k * N + j0);
            w[0] = wv.x; w[1] = wv.y;
        }
        #pragma unroll
        for (int i = 0; i < 4; ++i)
            #pragma unroll
            for (int c = 0; c < NCPT; ++c)
                acc[i][c] = fmaf(a[i], w[c], acc[i][c]);
    }
    #pragma unroll
    for (int i = 0; i < 4; ++i)
        #pragma unroll
        for (int c = 0; c < NCPT; ++c)
            outb[(r0 + i) * OUTS + j0 + c] = fmaxf(acc[i][c] + bias[j0 + c], 0.0f);
}

// Fused MLP + (linearized) scan.
// relu in the scan is the identity (gate>0, hidden0=0, sums of positives), so
//   hid_t[h] = hid_{t-1}[(h-s) mod H] + gate[t][h]
//   => hidden[b,h] = sum_t gate[t, b, (h - s*(T-1-t)) mod H]
//   => gate[t][j] scatters to h = (j + s*(T-1-t)) mod H   (PLUS base — R1 bugfix)
// Grid: 512 blocks = 2 t-halves x 256 batch rows. Block: 256 threads.
// tr = tid&7 -> 4-row group (32 rows/chunk), tc = tid>>3 -> col group.
__global__ __launch_bounds__(256, 2) void srnn_gate_scan(
    const float* __restrict__ x,
    const float* __restrict__ Wx, const float* __restrict__ bx,
    const float* __restrict__ W1, const float* __restrict__ b1,
    const float* __restrict__ W2, const float* __restrict__ b2,
    const float* __restrict__ W3, const float* __restrict__ b3,
    const float* __restrict__ W4, const float* __restrict__ b4,
    const float* __restrict__ W5, const float* __restrict__ b5,
    const int* __restrict__ shiftp,
    float* __restrict__ out)   // out[0..255]=output, out[256..]=hidden (pre-zeroed)
{
    __shared__ float sX[32 * 129];   // x chunk, padded: stride 129 -> 2-way-max LDS conflicts
    __shared__ float sA[32 * 105];   // act ping (stride 105: 4*105 % 32 == 4)
    __shared__ float sB[32 * 105];   // act pong
    __shared__ float accum[256];     // partial hidden for this block

    const int tid = threadIdx.x;
    const int b    = blockIdx.x & 255;
    const int half = blockIdx.x >> 8;
    const int tr = tid & 7;
    const int tc = tid >> 3;
    const int r0 = tr * 4;
    const int s = *shiftp;

    accum[tid] = 0.0f;
    __syncthreads();

    for (int chunk = 0; chunk < 16; ++chunk) {
        const int tbase = half * 512 + chunk * 32;

        // ---- stage 32 x-rows (x is [B,T,D]; row t reads x[b,t,:]) ----
        {
            const float* src = x + ((size_t)b * T_N + tbase) * D_N;
            #pragma unroll
            for (int q = 0; q < 4; ++q) {
                int sl = tid + q * 256;          // 1024 float4 slots
                int r  = sl >> 5;
                int c4 = sl & 31;
                float4 v = reinterpret_cast<const float4*>(src)[r * 32 + c4];
                float* dst = &sX[r * 129 + c4 * 4];
                dst[0] = v.x; dst[1] = v.y; dst[2] = v.z; dst[3] = v.w;
            }
        }
        __syncthreads();

        dense_relu<128, 100, 4, 129, 105>(W1, b1, sX, sB, r0, tc);  // L1
        __syncthreads();
        dense_relu<100, 100, 4, 105, 105>(W2, b2, sB, sA, r0, tc);  // L2
        __syncthreads();
        dense_relu<100, 100, 4, 105, 105>(W3, b3, sA, sB, r0, tc);  // L3
        __syncthreads();
        dense_relu<100,  50, 2, 105, 105>(W4, b4, sB, sA, r0, tc);  // L4
        __syncthreads();

        // ---- L5: 50->256 sigmoid (fx), Lx: 128->256 sigmoid, gate, accumulate ----
        {
            const int j0 = tc * 8;
            float fx[4][8];
            #pragma unroll
            for (int i = 0; i < 4; ++i)
                #pragma unroll
                for (int c = 0; c < 8; ++c) fx[i][c] = 0.0f;

            #pragma unroll 2
            for (int k = 0; k < 50; ++k) {
                float a[4];
                #pragma unroll
                for (int i = 0; i < 4; ++i) a[i] = sA[(r0 + i) * 105 + k];
                const float4 w0 = *reinterpret_cast<const float4*>(W5 + (size_t)k * 256 + j0);
                const float4 w1 = *reinterpret_cast<const float4*>(W5 + (size_t)k * 256 + j0 + 4);
                const float w[8] = {w0.x, w0.y, w0.z, w0.w, w1.x, w1.y, w1.z, w1.w};
                #pragma unroll
                for (int i = 0; i < 4; ++i)
                    #pragma unroll
                    for (int c = 0; c < 8; ++c)
                        fx[i][c] = fmaf(a[i], w[c], fx[i][c]);
            }
            float bb[8];
            #pragma unroll
            for (int c = 0; c < 8; ++c) bb[c] = b5[j0 + c];
            #pragma unroll
            for (int i = 0; i < 4; ++i)
                #pragma unroll
                for (int c = 0; c < 8; ++c)
                    fx[i][c] = sigmoid_f(fx[i][c] + bb[c]);

            float gx[4][8];
            #pragma unroll
            for (int i = 0; i < 4; ++i)
                #pragma unroll
                for (int c = 0; c < 8; ++c) gx[i][c] = 0.0f;

            #pragma unroll 2
            for (int k = 0; k < 128; ++k) {
                float a[4];
                #pragma unroll
                for (int i = 0; i < 4; ++i) a[i] = sX[(r0 + i) * 129 + k];
                const float4 w0 = *reinterpret_cast<const float4*>(Wx + (size_t)k * 256 + j0);
                const float4 w1 = *reinterpret_cast<const float4*>(Wx + (size_t)k * 256 + j0 + 4);
                const float w[8] = {w0.x, w0.y, w0.z, w0.w, w1.x, w1.y, w1.z, w1.w};
                #pragma unroll
                for (int i = 0; i < 4; ++i)
                    #pragma unroll
                    for (int c = 0; c < 8; ++c)
                        gx[i][c] = fmaf(a[i], w[c], gx[i][c]);
            }
            #pragma unroll
            for (int c = 0; c < 8; ++c) bb[c] = bx[j0 + c];

            #pragma unroll
            for (int i = 0; i < 4; ++i) {
                const int t = tbase + r0 + i;
                const int base = s * (T_N - 1 - t);
                #pragma unroll
                for (int c = 0; c < 8; ++c) {
                    const float g = fx[i][c] * sigmoid_f(gx[i][c] + bb[c]);
                    int v = j0 + c + base;                 // PLUS base (R1 fix)
                    v = ((v % H_N) + H_N) & (H_N - 1);
                    atomicAdd(&accum[v], g);   // per-t the h->v map is a bijection
                }
            }
        }
        __syncthreads();
    }

    // flush partial hidden (two blocks per b -> global atomic into zeroed out)
    atomicAdd(&out[256 + b * 256 + tid], accum[tid]);
}

// output[b] = sigmoid(hidden[b,:] @ Wo + bo)
__global__ __launch_bounds__(256) void srnn_output(
    const float* __restrict__ Wo, const float* __restrict__ bo,
    float* __restrict__ out)
{
    __shared__ float red[256];
    const int b = blockIdx.x, tid = threadIdx.x;
    red[tid] = out[256 + b * 256 + tid] * Wo[tid];
    __syncthreads();
    #pragma unroll
    for (int off = 128; off > 0; off >>= 1) {
        if (tid < off) red[tid] += red[tid + off];
        __syncthreads();
    }
    if (tid == 0) out[b] = sigmoid_f(red[0] + bo[0]);
}

extern "C" void kernel_launch(void* const* d_in, const int* in_sizes, int n_in,
                              void* d_out, int out_size, void* d_ws, size_t ws_size,
                              hipStream_t stream)
{
    const float* x  = (const float*)d_in[0];
    const float* Wx = (const float*)d_in[1];
    const float* bx = (const float*)d_in[2];
    const float* W1 = (const float*)d_in[3];
    const float* b1 = (const float*)d_in[4];
    const float* W2 = (const float*)d_in[5];
    const float* b2 = (const float*)d_in[6];
    const float* W3 = (const float*)d_in[7];
    const float* b3 = (const float*)d_in[8];
    const float* W4 = (const float*)d_in[9];
    const float* b4 = (const float*)d_in[10];
    const float* W5 = (const float*)d_in[11];
    const float* b5 = (const float*)d_in[12];
    const float* Wo = (const float*)d_in[13];
    const float* bo = (const float*)d_in[14];
    const int* shiftp = (const int*)d_in[15];
    float* out = (float*)d_out;

    // hidden is accumulated with atomics -> needs zero init (d_out is poisoned)
    hipMemsetAsync(d_out, 0, (size_t)out_size * sizeof(float), stream);

    srnn_gate_scan<<<dim3(512), dim3(256), 0, stream>>>(
        x, Wx, bx, W1, b1, W2, b2, W3, b3, W4, b4, W5, b5, shiftp, out);
    srnn_output<<<dim3(256), dim3(256), 0, stream>>>(Wo, bo, out);
}